// Round 4
// baseline (1196.636 us; speedup 1.0000x reference)
//
#include <hip/hip_runtime.h>
#include <math.h>

// Problem constants
#define NB   1024
#define NC   64
#define DIN  256
#define DH   128
#define DCP  32
#define NV   36

// Output flat offsets (fp32 elements), reference return order.
#define OFF0 0
#define OFF1 21233664
#define OFF2 23592960
#define OFF3 25952256
#define OFF4 26017792
#define OFF5 28377088
#define OFF6 28377089
#define OFF7 30474241

// Tile: 64 batch rows per block, 512 threads. Per-thread inner loops are
// identical to the verified 32-row kernel; only thread mappings change.
#define RT   64
#define THR  512

// LDS layout (float indices).
//  FST: persistent [128][68] activations (HsT then FsT), stride 68 (float4-aligned)
//  R2 : phase-scratch union (6976 floats)
//  R3 : CPS [64][36] (B->C) unioned with M[64][6]+PSIG[64] (D2b->D4)
#define FSS  68
#define SM_FST 0
#define SM_R2  8704
#define SM_R3  15680
#define SM_TOT 17984       // 71936 B -> 2 blocks/CU (2*71936 = 143872 <= 163840)

#define SM_XS  SM_R2           // A: [16][68] k-major X chunk
#define SM_W1C (SM_R2 + 1088)  // A: [16][128]
#define SM_W2S SM_R2           // B: [128][32]
#define SM_WM  SM_R2           // C: [33][128]
#define SM_WH  SM_R2           // D2: [16][80]
#define SM_HD  (SM_R2 + 1280)  // D2: [64][81]  (stride 81 kills write conflicts)
#define SM_HB  (SM_R2 + 6464)  // D2: [80]
#define SM_WD  SM_R2           // D4: [16][224] (216 cols padded to 224 for b128)
#define SM_DYN SM_R2           // D4: [64][109] half-buffer (reuses WD/HD space, both dead)
#define SM_CPS SM_R3           // [64][36]
#define SM_M   SM_R3           // [64][6]   (CPS dead by then)
#define SM_PSIG (SM_R3 + 384)  // [64]

__device__ __forceinline__ float sigm(float x) { return 1.0f / (1.0f + __expf(-x)); }
__device__ __forceinline__ float tanh5(float x) {
    x = fminf(fmaxf(5.0f * x, -15.0f), 15.0f);
    float z = __expf(2.0f * x);
    return (z - 1.0f) / (z + 1.0f);
}
__device__ __forceinline__ void geo(const float* p, float* m) {
    float sx = sigm(p[0]) + 0.01f;
    float sy = sigm(p[1]) + 0.01f;
    float th = p[2] * 6.28318530717958647692f;
    float sh = tanh5(p[3]);
    float tx = tanh5(p[4]);
    float ty = tanh5(p[5]);
    float cc = __cosf(th), ss = __sinf(th);
    m[0] =  sx * cc + sh * sy * ss;
    m[1] = -sx * ss + sh * sy * cc;
    m[2] = tx;
    m[3] = sy * ss;
    m[4] = sy * cc;
    m[5] = ty;
}

// Fused prep: zero the L2 scalar + features passthrough with coalesced dwords.
// ~26 us measured (R2). Runs first: feat becomes L3-warm for Phase A.
__global__ __launch_bounds__(256)
void prep_kernel(const float* __restrict__ feat, float* __restrict__ out)
{
    if (blockIdx.x == 0 && threadIdx.x == 0) out[OFF5] = 0.0f;
    const int n = NB * NC * DIN;               // 16,777,216
    const int stride = gridDim.x * 256;
    for (int i = blockIdx.x * 256 + threadIdx.x; i < n; i += stride)
        out[OFF7 + i] = feat[i];
}

__global__ __launch_bounds__(THR, 4)   // 4 waves/EU -> 2 blocks/CU (8 waves/block)
void caps_fused_kernel(const float* __restrict__ feat,
                       const float* __restrict__ w1,  const float* __restrict__ b1,
                       const float* __restrict__ w2,  const float* __restrict__ b2,
                       const float* __restrict__ wm,  const float* __restrict__ bm,
                       const float* __restrict__ wdy,
                       const float* __restrict__ wccr,const float* __restrict__ bccr,
                       const float* __restrict__ wpc, const float* __restrict__ bpc,
                       const float* __restrict__ wpv, const float* __restrict__ bpv,
                       const float* __restrict__ wsv, const float* __restrict__ bsv,
                       const float* __restrict__ cst,
                       float* __restrict__ out)
{
    __shared__ float sm[SM_TOT];
    const int t  = threadIdx.x;
    const int c  = blockIdx.y;
    const int rb = blockIdx.x * RT;

    float4 w2pf[2];   // Phase-B weights, prefetched during Phase A's last chunk

    // ===== Phase A: HsT = relu(X @ W1 + b1)^T, 64x128, K=256, chunks of 16 =====
    // R1 structure: register-prefetch chunk k+1 before compute of chunk k.
    // One 16x128 weight tile now feeds 64 output rows (2x amortization).
    {
        const int tx = t & 31;          // h-cols tx*4..+3
        const int ty = t >> 5;          // 0..15 -> b-rows ty*4..+3
        const int xrow = t >> 3;        // 0..63
        const int xk2  = (t & 7) * 2;
        const float* fsrc = &feat[(rb + xrow) * (NC * DIN) + c * DIN + xk2];
        const float* wsrc = &w1[c * (DIN * DH) + (t >> 5) * DH + (t & 31) * 4];
        float2 xr = *(const float2*)fsrc;
        float4 wr = *(const float4*)wsrc;
        float acc[4][4] = {};
        for (int k0 = 0; k0 < DIN; k0 += 16) {
            __syncthreads();
            // XS k-major [16][68]: reads are one broadcast b128 per kk
            sm[SM_XS + xk2 * FSS + xrow]       = xr.x;
            sm[SM_XS + (xk2 + 1) * FSS + xrow] = xr.y;
            *(float4*)&sm[SM_W1C + (t >> 5) * 128 + (t & 31) * 4] = wr;
            __syncthreads();
            if (k0 + 16 < DIN) {
                xr = *(const float2*)(fsrc + k0 + 16);
                wr = *(const float4*)(wsrc + (k0 + 16) * DH);
            } else {
                w2pf[0] = *(const float4*)&w2[c * (DH * DCP) + t * 4];
                w2pf[1] = *(const float4*)&w2[c * (DH * DCP) + (t + THR) * 4];
            }
#pragma unroll
            for (int kk = 0; kk < 16; ++kk) {
                const float4 av = *(const float4*)&sm[SM_XS + kk * FSS + ty * 4];   // broadcast
                const float4 bv = *(const float4*)&sm[SM_W1C + kk * 128 + tx * 4];
                acc[0][0] += av.x * bv.x; acc[0][1] += av.x * bv.y; acc[0][2] += av.x * bv.z; acc[0][3] += av.x * bv.w;
                acc[1][0] += av.y * bv.x; acc[1][1] += av.y * bv.y; acc[1][2] += av.y * bv.z; acc[1][3] += av.y * bv.w;
                acc[2][0] += av.z * bv.x; acc[2][1] += av.z * bv.y; acc[2][2] += av.z * bv.z; acc[2][3] += av.z * bv.w;
                acc[3][0] += av.w * bv.x; acc[3][1] += av.w * bv.y; acc[3][2] += av.w * bv.z; acc[3][3] += av.w * bv.w;
            }
        }
        const float4 bb = *(const float4*)&b1[c * DH + tx * 4];
        const float bbA[4] = { bb.x, bb.y, bb.z, bb.w };
#pragma unroll
        for (int j = 0; j < 4; ++j) {
            float4 vv;
            vv.x = fmaxf(acc[0][j] + bbA[j], 0.0f);
            vv.y = fmaxf(acc[1][j] + bbA[j], 0.0f);
            vv.z = fmaxf(acc[2][j] + bbA[j], 0.0f);
            vv.w = fmaxf(acc[3][j] + bbA[j], 0.0f);
            *(float4*)&sm[SM_FST + (tx * 4 + j) * FSS + ty * 4] = vv;
        }
    }

    // ===== Phase B: raw = relu(H @ W2 + b2), 64x32, K=128 =====
    __syncthreads();               // A readers done -> safe to overwrite XS/W1C
    *(float4*)&sm[SM_W2S + t * 4]         = w2pf[0];
    *(float4*)&sm[SM_W2S + (t + THR) * 4] = w2pf[1];
    __syncthreads();
    float4 wmpf[3];                // Phase-C weights, prefetched during B compute
    {
#pragma unroll
        for (int p = 0; p < 3; ++p) {
            const int idx = t + p * THR;
            if (idx < 1056)
                wmpf[p] = *(const float4*)&wm[c * (33 * DH) + idx * 4];
        }
        const int b  = t & 63;
        const int j4 = (t >> 6) << 2;    // wave-uniform -> W2S reads broadcast
        float acc[4] = {};
#pragma unroll 8
        for (int k = 0; k < DH; ++k) {
            const float h = sm[SM_FST + k * FSS + b];
            const float4 wv = *(const float4*)&sm[SM_W2S + k * DCP + j4];
            acc[0] += h * wv.x; acc[1] += h * wv.y; acc[2] += h * wv.z; acc[3] += h * wv.w;
        }
        const float4 b2v = *(const float4*)&b2[c * DCP + j4];
        float4 cv;
        cv.x = fmaxf(acc[0] + b2v.x, 0.0f);
        cv.y = fmaxf(acc[1] + b2v.y, 0.0f);
        cv.z = fmaxf(acc[2] + b2v.z, 0.0f);
        cv.w = fmaxf(acc[3] + b2v.w, 0.0f);
        *(float4*)&sm[SM_CPS + b * 36 + j4] = cv;
    }

    // ===== Phase C: caps_feat = relu([CP,1] @ Wm + bm), 64x128, K=33 =====
    __syncthreads();               // B readers done -> safe to overwrite W2S
#pragma unroll
    for (int p = 0; p < 3; ++p) {
        const int idx = t + p * THR;
        if (idx < 1056)
            *(float4*)&sm[SM_WM + idx * 4] = wmpf[p];
    }
    // OFF6 store pass: coalesced (32 consecutive lanes cover one 128 B row)
#pragma unroll
    for (int p = 0; p < 4; ++p) {
        const int item = t + p * THR;
        const int b = item >> 5, j = item & 31;
        out[OFF6 + ((rb + b) * NC + c) * DCP + j] = sm[SM_CPS + b * 36 + j];
    }
    __syncthreads();
    // --- D2 prefetch setup: per-p source pointer/stride resolved ONCE;
    // chunk-0 loads issue here and hide under C compute.
    const float* d2p[3]; int d2adv[3]; float d2msk[3], d2pf[3];
#pragma unroll
    for (int p = 0; p < 3; ++p) {
        const int idx = t + p * THR;            // dest offset in [16][80] == idx
        d2pf[p] = 0.0f; d2p[p] = wccr; d2adv[p] = 0; d2msk[p] = 0.0f;
        if (idx < 1280) {
            const int kp = idx / 80, colp = idx - kp * 80;
            const float* s; int st; float mk = 1.0f;
            if (colp < 6)       { s = &wccr[c * (DH * 6) + kp * 6 + colp];          st = 6;  }
            else if (colp == 6) { s = &wpc [c * DH + kp];                            st = 1;  }
            else if (colp < 43) { s = &wpv [c * (DH * NV) + kp * NV + (colp - 7)];   st = NV; }
            else if (colp < 79) { s = &wsv [c * (DH * NV) + kp * NV + (colp - 43)];  st = NV; }
            else                { s = &wccr[c * (DH * 6)]; st = 0; mk = 0.0f; }      // pad col 79
            d2pf[p]  = *s;
            d2p[p]   = s + st * 16;
            d2adv[p] = st * 16;
            d2msk[p] = mk;
        }
    }
    float bpf = 0.0f;
    if (t < 80) {
        if (t < 6)       bpf = bccr[c * 6 + t];
        else if (t == 6) bpf = bpc[c];
        else if (t < 43) bpf = bpv[c * NV + (t - 7)];
        else if (t < 79) bpf = bsv[c * NV + (t - 43)];
    }
    {
        const int b  = t & 63;
        const int nb = (t >> 6) << 4;   // wave-uniform -> WM reads broadcast
        float acc[16] = {};
#pragma unroll
        for (int k4 = 0; k4 < 8; ++k4) {
            const float4 a4 = *(const float4*)&sm[SM_CPS + b * 36 + k4 * 4];
            const float aA[4] = { a4.x, a4.y, a4.z, a4.w };
#pragma unroll
            for (int kk = 0; kk < 4; ++kk) {
                const int k = k4 * 4 + kk;
#pragma unroll
                for (int jq = 0; jq < 4; ++jq) {
                    const float4 wv = *(const float4*)&sm[SM_WM + k * DH + nb + jq * 4];
                    acc[jq*4+0] += aA[kk] * wv.x; acc[jq*4+1] += aA[kk] * wv.y;
                    acc[jq*4+2] += aA[kk] * wv.z; acc[jq*4+3] += aA[kk] * wv.w;
                }
            }
        }
        // exist column (k=32) is constant 1.0 -> plain add of WM row 32
#pragma unroll
        for (int jq = 0; jq < 4; ++jq) {
            const float4 wv = *(const float4*)&sm[SM_WM + 32 * DH + nb + jq * 4];
            acc[jq*4+0] += wv.x; acc[jq*4+1] += wv.y; acc[jq*4+2] += wv.z; acc[jq*4+3] += wv.w;
        }
#pragma unroll
        for (int jq = 0; jq < 4; ++jq) {
            const float4 bmv = *(const float4*)&bm[c * DH + nb + jq * 4];
            sm[SM_FST + (nb + jq*4 + 0) * FSS + b] = fmaxf(acc[jq*4+0] + bmv.x, 0.0f);
            sm[SM_FST + (nb + jq*4 + 1) * FSS + b] = fmaxf(acc[jq*4+1] + bmv.y, 0.0f);
            sm[SM_FST + (nb + jq*4 + 2) * FSS + b] = fmaxf(acc[jq*4+2] + bmv.z, 0.0f);
            sm[SM_FST + (nb + jq*4 + 3) * FSS + b] = fmaxf(acc[jq*4+3] + bmv.w, 0.0f);
        }
    }

    // ===== Phase D2: heads [ccr|pres_caps|pres_vote|scale_vote], 64x80, K=128 =====
    {
        const int txx = t & 15;   // cols txx*5..+4
        const int tyy = t >> 4;   // 0..31 -> rows tyy*2, tyy*2+1
        float acc[2][5] = {};
        for (int k0 = 0; k0 < DH; k0 += 16) {
            __syncthreads();      // first iter: WM readers (C) done before WH overwrite
#pragma unroll
            for (int p = 0; p < 3; ++p) {
                const int idx = t + p * THR;
                if (idx < 1280) sm[SM_WH + idx] = d2msk[p] * d2pf[p];
            }
            if (k0 == 0 && t < 80) sm[SM_HB + t] = bpf;
            __syncthreads();
            if (k0 + 16 < DH) {
#pragma unroll
                for (int p = 0; p < 3; ++p) {
                    if (t + p * THR < 1280) {
                        d2pf[p] = *d2p[p];
                        d2p[p] += d2adv[p];
                    }
                }
            }
#pragma unroll
            for (int kk = 0; kk < 16; ++kk) {
                const float2 av = *(const float2*)&sm[SM_FST + (k0 + kk) * FSS + tyy * 2];
#pragma unroll
                for (int j = 0; j < 5; ++j) {
                    const float w = sm[SM_WH + kk * 80 + txx * 5 + j];
                    acc[0][j] += av.x * w;
                    acc[1][j] += av.y * w;
                }
            }
        }
#pragma unroll
        for (int i = 0; i < 2; ++i)
#pragma unroll
            for (int j = 0; j < 5; ++j)
                sm[SM_HD + (tyy * 2 + i) * 81 + txx * 5 + j] = acc[i][j];
    }

    // --- D4 prefetch chunk 0: issued here so it hides under D2b/D2c epilogues.
    const float* d4p[4]; int d4dst[4]; unsigned d4v = 0; float2 d4pf[4];
    {
        const float* wdyb = &wdy[c * (DH * 216)];
#pragma unroll
        for (int p = 0; p < 4; ++p) {
            const int i2 = t + p * THR;        // float2 slot, valid < 1792
            d4dst[p] = -1;
            d4pf[p]  = make_float2(0.0f, 0.0f);
            d4p[p]   = wdyb;
            if (i2 < 1792) {
                const int e2  = i2 * 2;
                const int row = e2 / 224, col = e2 - row * 224;
                d4dst[p] = row * 224 + col;
                if (col < 216) {
                    d4v |= 1u << p;
                    d4p[p]  = wdyb + row * 216 + col;
                    d4pf[p] = *(const float2*)d4p[p];
                    d4p[p] += 16 * 216;
                }
            }
        }
    }
    __syncthreads();

    // D2b: ccr matrices + pres_caps sigmoid
    if (t < 64) {
        const int b = t;
        const float plc = sm[SM_HD + b * 81 + 6] + sm[SM_HB + 6];
        out[OFF3 + (rb + b) * NC + c] = plc;
        sm[SM_PSIG + b] = sigm(plc);
        float pp[6], m[6];
#pragma unroll
        for (int i = 0; i < 6; ++i) pp[i] = sm[SM_HD + b * 81 + i] + sm[SM_HB + i];
        geo(pp, m);
#pragma unroll
        for (int i = 0; i < 6; ++i) sm[SM_M + b * 6 + i] = m[i];
    }
    __syncthreads();

    // D2c: pres_vote / scale_vote epilogues (64*80 = 5120 items = 10*512)
#pragma unroll
    for (int p = 0; p < 10; ++p) {
        const int item = t + p * THR;
        const int b = item / 80, col = item % 80;
        if (col >= 7 && col < 79) {
            const float v = sm[SM_HD + b * 81 + col] + sm[SM_HB + col];
            const int base = ((rb + b) * NC + c) * NV;
            if (col < 43) {
                const int o = col - 7;
                out[OFF4 + base + o] = v;
                out[OFF2 + base + o] = sm[SM_PSIG + b] * sigm(v);
            } else {
                const int o = col - 43;
                float sp = v + 0.5f;
                sp = (sp > 15.0f) ? sp : log1pf(__expf(sp));
                out[OFF1 + base + o] = sp + 0.01f;
            }
        }
    }

    // ===== Phase D4: cpr_dynamic = F @ Wdyn, 64x216(pad 224), K=128 =====
    float l2loc = 0.0f;
    {
        const int g   = t & 63;    // col group: cols 4g..4g+3 (g>=54 = padding)
        const int ty8 = t >> 6;    // 0..7 -> rows ty8*8..+7 (wave-uniform -> broadcast)
        float acc[8][4] = {};
        for (int k0 = 0; k0 < DH; k0 += 16) {
            __syncthreads();       // first iter: HD readers (D2c) done before WD overwrite
#pragma unroll
            for (int p = 0; p < 4; ++p)
                if (d4dst[p] >= 0) *(float2*)&sm[SM_WD + d4dst[p]] = d4pf[p];
            __syncthreads();
            if (k0 + 16 < DH) {
#pragma unroll
                for (int p = 0; p < 4; ++p) {
                    if ((d4v >> p) & 1) {
                        d4pf[p] = *(const float2*)d4p[p];
                        d4p[p] += 16 * 216;
                    }
                }
            }
#pragma unroll
            for (int kk = 0; kk < 16; ++kk) {
                const float4 a0 = *(const float4*)&sm[SM_FST + (k0 + kk) * FSS + ty8 * 8];
                const float4 a1 = *(const float4*)&sm[SM_FST + (k0 + kk) * FSS + ty8 * 8 + 4];
                const float4 w  = *(const float4*)&sm[SM_WD + kk * 224 + g * 4];
                acc[0][0] += a0.x * w.x; acc[0][1] += a0.x * w.y; acc[0][2] += a0.x * w.z; acc[0][3] += a0.x * w.w;
                acc[1][0] += a0.y * w.x; acc[1][1] += a0.y * w.y; acc[1][2] += a0.y * w.z; acc[1][3] += a0.y * w.w;
                acc[2][0] += a0.z * w.x; acc[2][1] += a0.z * w.y; acc[2][2] += a0.z * w.z; acc[2][3] += a0.z * w.w;
                acc[3][0] += a0.w * w.x; acc[3][1] += a0.w * w.y; acc[3][2] += a0.w * w.z; acc[3][3] += a0.w * w.w;
                acc[4][0] += a1.x * w.x; acc[4][1] += a1.x * w.y; acc[4][2] += a1.x * w.z; acc[4][3] += a1.x * w.w;
                acc[5][0] += a1.y * w.x; acc[5][1] += a1.y * w.y; acc[5][2] += a1.y * w.z; acc[5][3] += a1.y * w.w;
                acc[6][0] += a1.z * w.x; acc[6][1] += a1.z * w.y; acc[6][2] += a1.z * w.z; acc[6][3] += a1.z * w.w;
                acc[7][0] += a1.w * w.x; acc[7][1] += a1.w * w.y; acc[7][2] += a1.w * w.z; acc[7][3] += a1.w * w.w;
            }
        }
        // two halves of 108 cols: write DYN, then epilogue
        for (int half = 0; half < 2; ++half) {
            __syncthreads();   // prior WD/DYN readers done
            if (g < 54 && (g >= 27) == (half == 1)) {
#pragma unroll
                for (int i = 0; i < 8; ++i)
#pragma unroll
                    for (int j = 0; j < 4; ++j)
                        sm[SM_DYN + (ty8 * 8 + i) * 109 + (g * 4 + j - half * 108)] = acc[i][j];
            }
            __syncthreads();
#pragma unroll
            for (int p = 0; p < 3; ++p) {
                const int item = t + p * THR;
                if (item < 1152) {               // 64 rows * 18 votes per half
                    const int b = item / 18, vh = item % 18;
                    const int v = half * 18 + vh;
                    float dyn[6], pose[6], mB[6];
                    float ss = 0.0f;
#pragma unroll
                    for (int j = 0; j < 6; ++j) {
                        dyn[j] = sm[SM_DYN + b * 109 + vh * 6 + j];
                        ss += dyn[j] * dyn[j];
                        pose[j] = dyn[j] + cst[c * (NV * 6) + v * 6 + j];
                    }
                    l2loc += ss;
                    geo(pose, mB);
                    const float A0 = sm[SM_M + b * 6 + 0], A1 = sm[SM_M + b * 6 + 1];
                    const float A2 = sm[SM_M + b * 6 + 2], A3 = sm[SM_M + b * 6 + 3];
                    const float A4 = sm[SM_M + b * 6 + 4], A5 = sm[SM_M + b * 6 + 5];
                    const int ob = (((rb + b) * NC + c) * NV + v) * 9;
                    out[OFF0 + ob + 0] = A0 * mB[0] + A1 * mB[3];
                    out[OFF0 + ob + 1] = A0 * mB[1] + A1 * mB[4];
                    out[OFF0 + ob + 2] = A0 * mB[2] + A1 * mB[5] + A2;
                    out[OFF0 + ob + 3] = A3 * mB[0] + A4 * mB[3];
                    out[OFF0 + ob + 4] = A3 * mB[1] + A4 * mB[4];
                    out[OFF0 + ob + 5] = A3 * mB[2] + A4 * mB[5] + A5;
                    out[OFF0 + ob + 6] = 0.0f;
                    out[OFF0 + ob + 7] = 0.0f;
                    out[OFF0 + ob + 8] = 1.0f;
                }
            }
        }
    }

    // L2 scalar: wave reduce, one atomic per wave; /B/2 = /2048
    l2loc += __shfl_down(l2loc, 32, 64);
    l2loc += __shfl_down(l2loc, 16, 64);
    l2loc += __shfl_down(l2loc, 8, 64);
    l2loc += __shfl_down(l2loc, 4, 64);
    l2loc += __shfl_down(l2loc, 2, 64);
    l2loc += __shfl_down(l2loc, 1, 64);
    if ((t & 63) == 0) atomicAdd(&out[OFF5], l2loc * (1.0f / 2048.0f));
}

extern "C" void kernel_launch(void* const* d_in, const int* in_sizes, int n_in,
                              void* d_out, int out_size, void* d_ws, size_t ws_size,
                              hipStream_t stream)
{
    const float* feat = (const float*)d_in[0];
    const float* w1   = (const float*)d_in[1];
    const float* b1   = (const float*)d_in[2];
    const float* w2   = (const float*)d_in[3];
    const float* b2   = (const float*)d_in[4];
    const float* wm   = (const float*)d_in[5];
    const float* bm   = (const float*)d_in[6];
    const float* wdy  = (const float*)d_in[7];
    const float* wccr = (const float*)d_in[8];
    const float* bccr = (const float*)d_in[9];
    const float* wpc  = (const float*)d_in[10];
    const float* bpc  = (const float*)d_in[11];
    const float* wpv  = (const float*)d_in[12];
    const float* bpv  = (const float*)d_in[13];
    const float* wsv  = (const float*)d_in[14];
    const float* bsv  = (const float*)d_in[15];
    const float* cst  = (const float*)d_in[16];
    float* out = (float*)d_out;

    prep_kernel<<<2048, 256, 0, stream>>>(feat, out);
    dim3 grid(NB / RT, NC);
    caps_fused_kernel<<<grid, THR, 0, stream>>>(feat, w1, b1, w2, b2, wm, bm, wdy,
                                                wccr, bccr, wpc, bpc, wpv, bpv,
                                                wsv, bsv, cst, out);
}

// Round 5
// 639.757 us; speedup vs baseline: 1.8705x; 1.8705x over previous
//
#include <hip/hip_runtime.h>
#include <math.h>

// Problem constants
#define NB   1024
#define NC   64
#define DIN  256
#define DH   128
#define DCP  32
#define NV   36

// Output flat offsets (fp32 elements), reference return order.
#define OFF0 0
#define OFF1 21233664
#define OFF2 23592960
#define OFF3 25952256
#define OFF4 26017792
#define OFF5 28377088
#define OFF6 28377089
#define OFF7 30474241

// LDS layout (float indices). Three regions:
//  FST: persistent [128][36] activations (HsT then FsT). stride 36 -> b64/b128-aligned reads
//  R2 : phase-scratch union (4352 floats)
//  R3 : CPS [32][36] (B->C) unioned with M[32][6]+PSIG[32] (D2b->D4)
#define SM_FST 0
#define SM_R2  4608
#define SM_R3  8960
#define SM_TOT 10112       // 40448 B -> 4 blocks/CU (4*40448 = 161792 <= 163840)

#define SM_XS  SM_R2           // A: [16][36] k-major X chunk (transposed)
#define SM_W1C (SM_R2 + 576)   // A: [16][128]
#define SM_W2S SM_R2           // B: [128][32]
#define SM_WM  SM_R2           // C: [33][128]
#define SM_WH  SM_R2           // D2: [16][80]
#define SM_HD  (SM_R2 + 1280)  // D2: [32][81]  (stride 81: kills write conflicts)
#define SM_HB  (SM_R2 + 3872)  // D2: [80]
#define SM_WD  SM_R2           // D4: [16][224] (216 cols padded to 224 for b128)
#define SM_DYN SM_R2           // D4: [32][109] half-buffer (reuses WD space)
#define SM_CPS SM_R3           // [32][36]  (stride 36 -> float4 reads; no exist col)
#define SM_M   SM_R3           // [32][6]   (CPS dead by then)
#define SM_PSIG (SM_R3 + 192)  // [32]

__device__ __forceinline__ float sigm(float x) { return 1.0f / (1.0f + __expf(-x)); }
__device__ __forceinline__ float tanh5(float x) {
    x = fminf(fmaxf(5.0f * x, -15.0f), 15.0f);
    float z = __expf(2.0f * x);
    return (z - 1.0f) / (z + 1.0f);
}
__device__ __forceinline__ void geo(const float* p, float* m) {
    float sx = sigm(p[0]) + 0.01f;
    float sy = sigm(p[1]) + 0.01f;
    float th = p[2] * 6.28318530717958647692f;
    float sh = tanh5(p[3]);
    float tx = tanh5(p[4]);
    float ty = tanh5(p[5]);
    float cc = __cosf(th), ss = __sinf(th);
    m[0] =  sx * cc + sh * sy * ss;
    m[1] = -sx * ss + sh * sy * cc;
    m[2] = tx;
    m[3] = sy * ss;
    m[4] = sy * cc;
    m[5] = ty;
}

__global__ void zero_l2_kernel(float* out) { out[OFF5] = 0.0f; }

__global__ __launch_bounds__(256, 4)   // 4 waves/EU -> 4 blocks/CU, VGPR<=128
void caps_fused_kernel(const float* __restrict__ feat,
                       const float* __restrict__ w1,  const float* __restrict__ b1,
                       const float* __restrict__ w2,  const float* __restrict__ b2,
                       const float* __restrict__ wm,  const float* __restrict__ bm,
                       const float* __restrict__ wdy,
                       const float* __restrict__ wccr,const float* __restrict__ bccr,
                       const float* __restrict__ wpc, const float* __restrict__ bpc,
                       const float* __restrict__ wpv, const float* __restrict__ bpv,
                       const float* __restrict__ wsv, const float* __restrict__ bsv,
                       const float* __restrict__ cst,
                       float* __restrict__ out)
{
    __shared__ float sm[SM_TOT];
    const int t  = threadIdx.x;
    const int c  = blockIdx.y;
    const int rb = blockIdx.x * 32;
    const int t4 = t * 4;

    float4 w2pf[4];   // Phase-B weights, prefetched during Phase A's last chunk

    // ===== Phase A: HsT = relu(X @ W1 + b1)^T, 32x128, K=256, chunks of 16 =====
    // Register-prefetch pipeline: loads for chunk k+1 issue BEFORE compute of
    // chunk k. Features passthrough (output 7) fused into the staging step —
    // fire-and-forget stores fill idle memory slots (verified best in R0).
    {
        const int tx = t & 31;          // h-cols tx*4..+3
        const int ty = t >> 5;          // b-rows ty*4..+3
        const int xrow = t >> 3, xk2 = (t & 7) * 2;
        const float* fsrc = &feat[(rb + xrow) * (NC * DIN) + c * DIN + xk2];
        const float* w1b_ = &w1[c * (DIN * DH)];
        float2 xr  = *(const float2*)fsrc;
        float4 wra = *(const float4*)(w1b_ + t4);
        float4 wrb = *(const float4*)(w1b_ + 1024 + t4);
        float acc[4][4] = {};
        for (int k0 = 0; k0 < DIN; k0 += 16) {
            __syncthreads();
            // XS is k-major [16][36]: write transposed so reads are one b128
            sm[SM_XS + xk2 * 36 + xrow]       = xr.x;
            sm[SM_XS + (xk2 + 1) * 36 + xrow] = xr.y;
            {   // features passthrough (OFF7 odd -> scalar dword stores)
                const int gi = (rb + xrow) * (NC * DIN) + c * DIN + k0 + xk2;
                out[OFF7 + gi]     = xr.x;
                out[OFF7 + gi + 1] = xr.y;
            }
            *(float4*)&sm[SM_W1C + t4]        = wra;
            *(float4*)&sm[SM_W1C + 1024 + t4] = wrb;
            __syncthreads();
            if (k0 + 16 < DIN) {
                xr  = *(const float2*)(fsrc + k0 + 16);
                wra = *(const float4*)(w1b_ + (k0 + 16) * DH + t4);
                wrb = *(const float4*)(w1b_ + (k0 + 16) * DH + 1024 + t4);
            } else {
#pragma unroll
                for (int p = 0; p < 4; ++p)
                    w2pf[p] = *(const float4*)&w2[c * (DH * DCP) + (t + p * 256) * 4];
            }
#pragma unroll
            for (int kk = 0; kk < 16; ++kk) {
                const float4 av = *(const float4*)&sm[SM_XS + kk * 36 + ty * 4];   // broadcast
                const float4 bv = *(const float4*)&sm[SM_W1C + kk * DH + tx * 4];
                acc[0][0] += av.x * bv.x; acc[0][1] += av.x * bv.y; acc[0][2] += av.x * bv.z; acc[0][3] += av.x * bv.w;
                acc[1][0] += av.y * bv.x; acc[1][1] += av.y * bv.y; acc[1][2] += av.y * bv.z; acc[1][3] += av.y * bv.w;
                acc[2][0] += av.z * bv.x; acc[2][1] += av.z * bv.y; acc[2][2] += av.z * bv.z; acc[2][3] += av.z * bv.w;
                acc[3][0] += av.w * bv.x; acc[3][1] += av.w * bv.y; acc[3][2] += av.w * bv.z; acc[3][3] += av.w * bv.w;
            }
        }
        const float4 bb = *(const float4*)&b1[c * DH + tx * 4];
        const float bbA[4] = { bb.x, bb.y, bb.z, bb.w };
#pragma unroll
        for (int j = 0; j < 4; ++j) {
            float4 vv;
            vv.x = fmaxf(acc[0][j] + bbA[j], 0.0f);
            vv.y = fmaxf(acc[1][j] + bbA[j], 0.0f);
            vv.z = fmaxf(acc[2][j] + bbA[j], 0.0f);
            vv.w = fmaxf(acc[3][j] + bbA[j], 0.0f);
            *(float4*)&sm[SM_FST + (tx * 4 + j) * 36 + ty * 4] = vv;  // 4 rows contiguous
        }
    }

    // ===== Phase B: raw = relu(H @ W2 + b2), 32x32, K=128 =====
    __syncthreads();               // A readers done -> safe to overwrite XS/W1C
#pragma unroll
    for (int p = 0; p < 4; ++p)
        *(float4*)&sm[SM_W2S + t4 + p * 1024] = w2pf[p];
    __syncthreads();
    float4 wmpf[5];                // Phase-C weights, prefetched during B compute
    {
#pragma unroll
        for (int p = 0; p < 5; ++p) {
            const int idx = t + p * 256;
            if (idx < 1056)
                wmpf[p] = *(const float4*)&wm[c * (33 * DH) + idx * 4];
        }
        const int b  = t & 31;
        const int j4 = (t >> 5) << 2;
        float acc[4] = {};
#pragma unroll 8
        for (int k = 0; k < DH; ++k) {
            const float h = sm[SM_FST + k * 36 + b];
            const float4 wv = *(const float4*)&sm[SM_W2S + k * DCP + j4];
            acc[0] += h * wv.x; acc[1] += h * wv.y; acc[2] += h * wv.z; acc[3] += h * wv.w;
        }
        const float4 b2v = *(const float4*)&b2[c * DCP + j4];
        float4 cv;
        cv.x = fmaxf(acc[0] + b2v.x, 0.0f);
        cv.y = fmaxf(acc[1] + b2v.y, 0.0f);
        cv.z = fmaxf(acc[2] + b2v.z, 0.0f);
        cv.w = fmaxf(acc[3] + b2v.w, 0.0f);
        *(float4*)&sm[SM_CPS + b * 36 + j4] = cv;
    }

    // ===== Phase C: caps_feat = relu([CP,1] @ Wm + bm), 32x128, K=33 =====
    __syncthreads();               // B done -> CPS complete, W2S dead
#pragma unroll
    for (int p = 0; p < 5; ++p) {
        const int idx = t + p * 256;
        if (idx < 1056)
            *(float4*)&sm[SM_WM + idx * 4] = wmpf[p];
    }
    // OFF6 store pass: coalesced (32 consecutive lanes cover one 128 B row;
    // replaces Phase B's 16 B/lane scattered stores -> kills RFO amplification)
#pragma unroll
    for (int p = 0; p < 4; ++p) {
        const int item = t + p * 256;
        const int b = item >> 5, j = item & 31;
        out[OFF6 + ((rb + b) * NC + c) * DCP + j] = sm[SM_CPS + b * 36 + j];
    }
    __syncthreads();
    // --- D2 prefetch setup: per-p source pointer/stride resolved ONCE (no
    // per-chunk div/mod/branches); chunk0 loads issue now, hide under C compute.
    const float* d2p[5]; int d2adv[5], d2dst[5]; float d2msk[5], d2pf[5];
#pragma unroll
    for (int p = 0; p < 5; ++p) {
        const int idx = t + p * 256;            // dest offset in [16][80] == idx
        const int kp = idx / 80, colp = idx - kp * 80;
        d2dst[p] = idx;
        const float* s; int st; float mk = 1.0f;
        if (colp < 6)       { s = &wccr[c * (DH * 6) + kp * 6 + colp];          st = 6;  }
        else if (colp == 6) { s = &wpc [c * DH + kp];                            st = 1;  }
        else if (colp < 43) { s = &wpv [c * (DH * NV) + kp * NV + (colp - 7)];   st = NV; }
        else if (colp < 79) { s = &wsv [c * (DH * NV) + kp * NV + (colp - 43)];  st = NV; }
        else                { s = &wccr[c * (DH * 6)]; st = 0; mk = 0.0f; }      // pad col 79
        d2pf[p]  = *s;
        d2p[p]   = s + st * 16;
        d2adv[p] = st * 16;
        d2msk[p] = mk;
    }
    float bpf = 0.0f;
    if (t < 80) {
        if (t < 6)       bpf = bccr[c * 6 + t];
        else if (t == 6) bpf = bpc[c];
        else if (t < 43) bpf = bpv[c * NV + (t - 7)];
        else if (t < 79) bpf = bsv[c * NV + (t - 43)];
    }
    {
        const int b  = t & 31;
        const int nb = (t >> 5) << 4;
        float acc[16] = {};
#pragma unroll
        for (int k4 = 0; k4 < 8; ++k4) {
            const float4 a4 = *(const float4*)&sm[SM_CPS + b * 36 + k4 * 4];
            const float aA[4] = { a4.x, a4.y, a4.z, a4.w };
#pragma unroll
            for (int kk = 0; kk < 4; ++kk) {
                const int k = k4 * 4 + kk;
#pragma unroll
                for (int jq = 0; jq < 4; ++jq) {
                    const float4 wv = *(const float4*)&sm[SM_WM + k * DH + nb + jq * 4];
                    acc[jq*4+0] += aA[kk] * wv.x; acc[jq*4+1] += aA[kk] * wv.y;
                    acc[jq*4+2] += aA[kk] * wv.z; acc[jq*4+3] += aA[kk] * wv.w;
                }
            }
        }
        // exist column (k=32) is constant 1.0 -> plain add of WM row 32
#pragma unroll
        for (int jq = 0; jq < 4; ++jq) {
            const float4 wv = *(const float4*)&sm[SM_WM + 32 * DH + nb + jq * 4];
            acc[jq*4+0] += wv.x; acc[jq*4+1] += wv.y; acc[jq*4+2] += wv.z; acc[jq*4+3] += wv.w;
        }
#pragma unroll
        for (int jq = 0; jq < 4; ++jq) {
            const float4 bmv = *(const float4*)&bm[c * DH + nb + jq * 4];
            sm[SM_FST + (nb + jq*4 + 0) * 36 + b] = fmaxf(acc[jq*4+0] + bmv.x, 0.0f);
            sm[SM_FST + (nb + jq*4 + 1) * 36 + b] = fmaxf(acc[jq*4+1] + bmv.y, 0.0f);
            sm[SM_FST + (nb + jq*4 + 2) * 36 + b] = fmaxf(acc[jq*4+2] + bmv.z, 0.0f);
            sm[SM_FST + (nb + jq*4 + 3) * 36 + b] = fmaxf(acc[jq*4+3] + bmv.w, 0.0f);
        }
    }

    // ===== Phase D2: heads [ccr|pres_caps|pres_vote|scale_vote], 32x80, K=128 =====
    {
        const int txx = t & 15;   // cols txx*5..+4
        const int tyy = t >> 4;   // rows tyy*2, tyy*2+1
        float acc[2][5] = {};
        for (int k0 = 0; k0 < DH; k0 += 16) {
            __syncthreads();      // first iter: WM readers (C) done before WH overwrite
#pragma unroll
            for (int p = 0; p < 5; ++p)
                sm[SM_WH + d2dst[p]] = d2msk[p] * d2pf[p];
            if (k0 == 0 && t < 80) sm[SM_HB + t] = bpf;
            __syncthreads();
            if (k0 + 16 < DH) {
#pragma unroll
                for (int p = 0; p < 5; ++p) {
                    d2pf[p] = *d2p[p];
                    d2p[p] += d2adv[p];
                }
            }
#pragma unroll
            for (int kk = 0; kk < 16; ++kk) {
                const float2 av = *(const float2*)&sm[SM_FST + (k0 + kk) * 36 + tyy * 2];
#pragma unroll
                for (int j = 0; j < 5; ++j) {
                    const float w = sm[SM_WH + kk * 80 + txx * 5 + j];
                    acc[0][j] += av.x * w;
                    acc[1][j] += av.y * w;
                }
            }
        }
#pragma unroll
        for (int i = 0; i < 2; ++i)
#pragma unroll
            for (int j = 0; j < 5; ++j)
                sm[SM_HD + (tyy * 2 + i) * 81 + txx * 5 + j] = acc[i][j];
    }

    // --- D4 prefetch chunk 0: issued here so it hides under D2b/D2c epilogues.
    const float* d4p[7]; int d4dst[7]; unsigned d4v = 0; float2 d4pf[7];
    {
        const float* wdyb = &wdy[c * (DH * 216)];
#pragma unroll
        for (int p = 0; p < 7; ++p) {
            const int e2  = (t + p * 256) * 2;
            const int row = e2 / 224, col = e2 - row * 224;
            d4dst[p] = row * 224 + col;
            d4pf[p]  = make_float2(0.0f, 0.0f);
            d4p[p]   = wdyb;
            if (col < 216) {
                d4v |= 1u << p;
                d4p[p]  = wdyb + row * 216 + col;
                d4pf[p] = *(const float2*)d4p[p];
                d4p[p] += 16 * 216;
            }
        }
    }
    __syncthreads();

    // D2b: ccr matrices + pres_caps sigmoid
    if (t < 32) {
        const int b = t;
        const float plc = sm[SM_HD + b * 81 + 6] + sm[SM_HB + 6];
        out[OFF3 + (rb + b) * NC + c] = plc;
        sm[SM_PSIG + b] = sigm(plc);
        float pp[6], m[6];
#pragma unroll
        for (int i = 0; i < 6; ++i) pp[i] = sm[SM_HD + b * 81 + i] + sm[SM_HB + i];
        geo(pp, m);
#pragma unroll
        for (int i = 0; i < 6; ++i) sm[SM_M + b * 6 + i] = m[i];
    }
    __syncthreads();

    // D2c: pres_vote / scale_vote epilogues
#pragma unroll
    for (int p = 0; p < 10; ++p) {
        const int item = t + p * 256;
        const int b = item / 80, col = item % 80;
        if (col >= 7 && col < 79) {
            const float v = sm[SM_HD + b * 81 + col] + sm[SM_HB + col];
            const int base = ((rb + b) * NC + c) * NV;
            if (col < 43) {
                const int o = col - 7;
                out[OFF4 + base + o] = v;
                out[OFF2 + base + o] = sm[SM_PSIG + b] * sigm(v);
            } else {
                const int o = col - 43;
                float sp = v + 0.5f;
                sp = (sp > 15.0f) ? sp : log1pf(__expf(sp));
                out[OFF1 + base + o] = sp + 0.01f;
            }
        }
    }

    // ===== Phase D4: cpr_dynamic = F @ Wdyn, 32x216(pad 224), K=128 =====
    float l2loc = 0.0f;
    {
        const int g   = t & 63;    // col group: cols 4g..4g+3 (g>=54 = padding)
        const int ty4 = t >> 6;    // rows ty4*8..+7 (wave-uniform -> broadcast reads)
        float acc[8][4] = {};
        for (int k0 = 0; k0 < DH; k0 += 16) {
            __syncthreads();       // first iter: HD readers (D2c) done before WD overwrite
#pragma unroll
            for (int p = 0; p < 7; ++p)
                *(float2*)&sm[SM_WD + d4dst[p]] = d4pf[p];
            __syncthreads();
            if (k0 + 16 < DH) {
#pragma unroll
                for (int p = 0; p < 7; ++p) {
                    if ((d4v >> p) & 1) {
                        d4pf[p] = *(const float2*)d4p[p];
                        d4p[p] += 16 * 216;
                    }
                }
            }
#pragma unroll
            for (int kk = 0; kk < 16; ++kk) {
                const float4 a0 = *(const float4*)&sm[SM_FST + (k0 + kk) * 36 + ty4 * 8];
                const float4 a1 = *(const float4*)&sm[SM_FST + (k0 + kk) * 36 + ty4 * 8 + 4];
                const float4 w  = *(const float4*)&sm[SM_WD + kk * 224 + g * 4];
                acc[0][0] += a0.x * w.x; acc[0][1] += a0.x * w.y; acc[0][2] += a0.x * w.z; acc[0][3] += a0.x * w.w;
                acc[1][0] += a0.y * w.x; acc[1][1] += a0.y * w.y; acc[1][2] += a0.y * w.z; acc[1][3] += a0.y * w.w;
                acc[2][0] += a0.z * w.x; acc[2][1] += a0.z * w.y; acc[2][2] += a0.z * w.z; acc[2][3] += a0.z * w.w;
                acc[3][0] += a0.w * w.x; acc[3][1] += a0.w * w.y; acc[3][2] += a0.w * w.z; acc[3][3] += a0.w * w.w;
                acc[4][0] += a1.x * w.x; acc[4][1] += a1.x * w.y; acc[4][2] += a1.x * w.z; acc[4][3] += a1.x * w.w;
                acc[5][0] += a1.y * w.x; acc[5][1] += a1.y * w.y; acc[5][2] += a1.y * w.z; acc[5][3] += a1.y * w.w;
                acc[6][0] += a1.z * w.x; acc[6][1] += a1.z * w.y; acc[6][2] += a1.z * w.z; acc[6][3] += a1.z * w.w;
                acc[7][0] += a1.w * w.x; acc[7][1] += a1.w * w.y; acc[7][2] += a1.w * w.z; acc[7][3] += a1.w * w.w;
            }
        }
        // two halves of 108 cols: write DYN, then epilogue
        for (int half = 0; half < 2; ++half) {
            __syncthreads();   // prior WD/DYN readers done
            if (g < 54 && (g >= 27) == (half == 1)) {
#pragma unroll
                for (int i = 0; i < 8; ++i)
#pragma unroll
                    for (int j = 0; j < 4; ++j)
                        sm[SM_DYN + (ty4 * 8 + i) * 109 + (g * 4 + j - half * 108)] = acc[i][j];
            }
            __syncthreads();
#pragma unroll
            for (int p = 0; p < 3; ++p) {
                const int item = t + p * 256;
                if (item < 576) {
                    const int b = item / 18, vh = item % 18;
                    const int v = half * 18 + vh;
                    float dyn[6], pose[6], mB[6];
                    float ss = 0.0f;
#pragma unroll
                    for (int j = 0; j < 6; ++j) {
                        dyn[j] = sm[SM_DYN + b * 109 + vh * 6 + j];
                        ss += dyn[j] * dyn[j];
                        pose[j] = dyn[j] + cst[c * (NV * 6) + v * 6 + j];
                    }
                    l2loc += ss;
                    geo(pose, mB);
                    const float A0 = sm[SM_M + b * 6 + 0], A1 = sm[SM_M + b * 6 + 1];
                    const float A2 = sm[SM_M + b * 6 + 2], A3 = sm[SM_M + b * 6 + 3];
                    const float A4 = sm[SM_M + b * 6 + 4], A5 = sm[SM_M + b * 6 + 5];
                    const int ob = (((rb + b) * NC + c) * NV + v) * 9;
                    out[OFF0 + ob + 0] = A0 * mB[0] + A1 * mB[3];
                    out[OFF0 + ob + 1] = A0 * mB[1] + A1 * mB[4];
                    out[OFF0 + ob + 2] = A0 * mB[2] + A1 * mB[5] + A2;
                    out[OFF0 + ob + 3] = A3 * mB[0] + A4 * mB[3];
                    out[OFF0 + ob + 4] = A3 * mB[1] + A4 * mB[4];
                    out[OFF0 + ob + 5] = A3 * mB[2] + A4 * mB[5] + A5;
                    out[OFF0 + ob + 6] = 0.0f;
                    out[OFF0 + ob + 7] = 0.0f;
                    out[OFF0 + ob + 8] = 1.0f;
                }
            }
        }
    }

    // L2 scalar: wave reduce, one atomic per wave; /B/2 = /2048
    l2loc += __shfl_down(l2loc, 32, 64);
    l2loc += __shfl_down(l2loc, 16, 64);
    l2loc += __shfl_down(l2loc, 8, 64);
    l2loc += __shfl_down(l2loc, 4, 64);
    l2loc += __shfl_down(l2loc, 2, 64);
    l2loc += __shfl_down(l2loc, 1, 64);
    if ((t & 63) == 0) atomicAdd(&out[OFF5], l2loc * (1.0f / 2048.0f));
}

extern "C" void kernel_launch(void* const* d_in, const int* in_sizes, int n_in,
                              void* d_out, int out_size, void* d_ws, size_t ws_size,
                              hipStream_t stream)
{
    const float* feat = (const float*)d_in[0];
    const float* w1   = (const float*)d_in[1];
    const float* b1   = (const float*)d_in[2];
    const float* w2   = (const float*)d_in[3];
    const float* b2   = (const float*)d_in[4];
    const float* wm   = (const float*)d_in[5];
    const float* bm   = (const float*)d_in[6];
    const float* wdy  = (const float*)d_in[7];
    const float* wccr = (const float*)d_in[8];
    const float* bccr = (const float*)d_in[9];
    const float* wpc  = (const float*)d_in[10];
    const float* bpc  = (const float*)d_in[11];
    const float* wpv  = (const float*)d_in[12];
    const float* bpv  = (const float*)d_in[13];
    const float* wsv  = (const float*)d_in[14];
    const float* bsv  = (const float*)d_in[15];
    const float* cst  = (const float*)d_in[16];
    float* out = (float*)d_out;

    zero_l2_kernel<<<1, 1, 0, stream>>>(out);
    dim3 grid(NB / 32, NC);
    caps_fused_kernel<<<grid, 256, 0, stream>>>(feat, w1, b1, w2, b2, wm, bm, wdy,
                                                wccr, bccr, wpc, bpc, wpv, bpv,
                                                wsv, bsv, cst, out);
}

// Round 6
// 599.120 us; speedup vs baseline: 1.9973x; 1.0678x over previous
//
#include <hip/hip_runtime.h>
#include <math.h>

// Problem constants
#define NB   1024
#define NC   64
#define DIN  256
#define DH   128
#define DCP  32
#define NV   36

// Output flat offsets (fp32 elements), reference return order.
#define OFF0 0
#define OFF1 21233664
#define OFF2 23592960
#define OFF3 25952256
#define OFF4 26017792
#define OFF5 28377088
#define OFF6 28377089
#define OFF7 30474241

// LDS layout (float indices). Three regions:
//  FST: persistent [128][36] activations (HsT then FsT). stride 36 -> b64/b128-aligned reads
//  R2 : phase-scratch union (4352 floats)
//  R3 : CPS [32][36] (B->C) unioned with M[32][6]+PSIG[32] (D2b->D4)
#define SM_FST 0
#define SM_R2  4608
#define SM_R3  8960
#define SM_TOT 10112       // 40448 B -> 4 blocks/CU (4*40448 = 161792 <= 163840)

#define SM_XS  SM_R2           // A: [16][36] k-major X chunk (transposed)
#define SM_W1C (SM_R2 + 576)   // A: [16][128]
#define SM_W2S SM_R2           // B: [128][32]
#define SM_WM  SM_R2           // C: [33][128]
#define SM_WH  SM_R2           // D2: [16][80]
#define SM_HD  (SM_R2 + 1280)  // D2: [32][81]  (stride 81: kills write conflicts)
#define SM_HB  (SM_R2 + 3872)  // D2: [80]
#define SM_WD  SM_R2           // D4: [16][224] (216 cols padded to 224 for b128)
#define SM_DYN SM_R2           // D4: [32][109] half-buffer (reuses WD space)
#define SM_CPS SM_R3           // [32][36]  (stride 36 -> float4 reads; no exist col)
#define SM_M   SM_R3           // [32][6]   (CPS dead by then)
#define SM_PSIG (SM_R3 + 192)  // [32]

__device__ __forceinline__ float sigm(float x) { return 1.0f / (1.0f + __expf(-x)); }
__device__ __forceinline__ float tanh5(float x) {
    x = fminf(fmaxf(5.0f * x, -15.0f), 15.0f);
    float z = __expf(2.0f * x);
    return (z - 1.0f) / (z + 1.0f);
}
__device__ __forceinline__ void geo(const float* p, float* m) {
    float sx = sigm(p[0]) + 0.01f;
    float sy = sigm(p[1]) + 0.01f;
    float th = p[2] * 6.28318530717958647692f;
    float sh = tanh5(p[3]);
    float tx = tanh5(p[4]);
    float ty = tanh5(p[5]);
    float cc = __cosf(th), ss = __sinf(th);
    m[0] =  sx * cc + sh * sy * ss;
    m[1] = -sx * ss + sh * sy * cc;
    m[2] = tx;
    m[3] = sy * ss;
    m[4] = sy * cc;
    m[5] = ty;
}

__global__ void zero_l2_kernel(float* out) { out[OFF5] = 0.0f; }

__global__ __launch_bounds__(256, 4)   // 4 waves/EU -> 4 blocks/CU, VGPR<=128
void caps_fused_kernel(const float* __restrict__ feat,
                       const float* __restrict__ w1,  const float* __restrict__ b1,
                       const float* __restrict__ w2,  const float* __restrict__ b2,
                       const float* __restrict__ wm,  const float* __restrict__ bm,
                       const float* __restrict__ wdy,
                       const float* __restrict__ wccr,const float* __restrict__ bccr,
                       const float* __restrict__ wpc, const float* __restrict__ bpc,
                       const float* __restrict__ wpv, const float* __restrict__ bpv,
                       const float* __restrict__ wsv, const float* __restrict__ bsv,
                       const float* __restrict__ cst,
                       float* __restrict__ out)
{
    __shared__ float sm[SM_TOT];
    const int t  = threadIdx.x;
    // XCD-aware swizzle: workgroup->XCD dispatch is round-robin (n % 8), so
    // give XCD x the capsules c in [x*8, x*8+8). All 32 row-blocks of a c then
    // share one XCD's L2 -> per-XCD weight working set ~2.2 MB (L2-resident)
    // instead of all 64 capsules (~13.7 MB, thrash). Bijection: worst case neutral.
    const int n  = blockIdx.x;
    const int c  = ((n & 7) << 3) | ((n >> 3) & 7);
    const int rb = (n >> 6) << 5;
    const int t4 = t * 4;

    float4 w2pf[4];   // Phase-B weights, prefetched during Phase A's last chunk

    // ===== Phase A: HsT = relu(X @ W1 + b1)^T, 32x128, K=256, chunks of 16 =====
    // Register-prefetch pipeline: loads for chunk k+1 issue BEFORE compute of
    // chunk k. Features passthrough (output 7) fused into the staging step.
    {
        const int tx = t & 31;          // h-cols tx*4..+3
        const int ty = t >> 5;          // b-rows ty*4..+3
        const int xrow = t >> 3, xk2 = (t & 7) * 2;
        const float* fsrc = &feat[(rb + xrow) * (NC * DIN) + c * DIN + xk2];
        const float* w1b_ = &w1[c * (DIN * DH)];
        float2 xr  = *(const float2*)fsrc;
        float4 wra = *(const float4*)(w1b_ + t4);
        float4 wrb = *(const float4*)(w1b_ + 1024 + t4);
        float acc[4][4] = {};
        for (int k0 = 0; k0 < DIN; k0 += 16) {
            __syncthreads();
            // XS is k-major [16][36]: write transposed so reads are one b128
            sm[SM_XS + xk2 * 36 + xrow]       = xr.x;
            sm[SM_XS + (xk2 + 1) * 36 + xrow] = xr.y;
            {   // features passthrough (OFF7 odd -> scalar dword stores)
                const int gi = (rb + xrow) * (NC * DIN) + c * DIN + k0 + xk2;
                out[OFF7 + gi]     = xr.x;
                out[OFF7 + gi + 1] = xr.y;
            }
            *(float4*)&sm[SM_W1C + t4]        = wra;
            *(float4*)&sm[SM_W1C + 1024 + t4] = wrb;
            __syncthreads();
            if (k0 + 16 < DIN) {
                xr  = *(const float2*)(fsrc + k0 + 16);
                wra = *(const float4*)(w1b_ + (k0 + 16) * DH + t4);
                wrb = *(const float4*)(w1b_ + (k0 + 16) * DH + 1024 + t4);
            } else {
#pragma unroll
                for (int p = 0; p < 4; ++p)
                    w2pf[p] = *(const float4*)&w2[c * (DH * DCP) + (t + p * 256) * 4];
            }
#pragma unroll
            for (int kk = 0; kk < 16; ++kk) {
                const float4 av = *(const float4*)&sm[SM_XS + kk * 36 + ty * 4];   // broadcast
                const float4 bv = *(const float4*)&sm[SM_W1C + kk * DH + tx * 4];
                acc[0][0] += av.x * bv.x; acc[0][1] += av.x * bv.y; acc[0][2] += av.x * bv.z; acc[0][3] += av.x * bv.w;
                acc[1][0] += av.y * bv.x; acc[1][1] += av.y * bv.y; acc[1][2] += av.y * bv.z; acc[1][3] += av.y * bv.w;
                acc[2][0] += av.z * bv.x; acc[2][1] += av.z * bv.y; acc[2][2] += av.z * bv.z; acc[2][3] += av.z * bv.w;
                acc[3][0] += av.w * bv.x; acc[3][1] += av.w * bv.y; acc[3][2] += av.w * bv.z; acc[3][3] += av.w * bv.w;
            }
        }
        const float4 bb = *(const float4*)&b1[c * DH + tx * 4];
        const float bbA[4] = { bb.x, bb.y, bb.z, bb.w };
#pragma unroll
        for (int j = 0; j < 4; ++j) {
            float4 vv;
            vv.x = fmaxf(acc[0][j] + bbA[j], 0.0f);
            vv.y = fmaxf(acc[1][j] + bbA[j], 0.0f);
            vv.z = fmaxf(acc[2][j] + bbA[j], 0.0f);
            vv.w = fmaxf(acc[3][j] + bbA[j], 0.0f);
            *(float4*)&sm[SM_FST + (tx * 4 + j) * 36 + ty * 4] = vv;  // 4 rows contiguous
        }
    }

    // ===== Phase B: raw = relu(H @ W2 + b2), 32x32, K=128 =====
    __syncthreads();               // A readers done -> safe to overwrite XS/W1C
#pragma unroll
    for (int p = 0; p < 4; ++p)
        *(float4*)&sm[SM_W2S + t4 + p * 1024] = w2pf[p];
    __syncthreads();
    float4 wmpf[5];                // Phase-C weights, prefetched during B compute
    {
#pragma unroll
        for (int p = 0; p < 5; ++p) {
            const int idx = t + p * 256;
            if (idx < 1056)
                wmpf[p] = *(const float4*)&wm[c * (33 * DH) + idx * 4];
        }
        const int b  = t & 31;
        const int j4 = (t >> 5) << 2;
        float acc[4] = {};
#pragma unroll 8
        for (int k = 0; k < DH; ++k) {
            const float h = sm[SM_FST + k * 36 + b];
            const float4 wv = *(const float4*)&sm[SM_W2S + k * DCP + j4];
            acc[0] += h * wv.x; acc[1] += h * wv.y; acc[2] += h * wv.z; acc[3] += h * wv.w;
        }
        const float4 b2v = *(const float4*)&b2[c * DCP + j4];
        const float b2A[4] = { b2v.x, b2v.y, b2v.z, b2v.w };
#pragma unroll
        for (int jj = 0; jj < 4; ++jj) {
            const float v = fmaxf(acc[jj] + b2A[jj], 0.0f);
            out[OFF6 + ((rb + b) * NC + c) * DCP + j4 + jj] = v;   // OFF6 odd -> scalar
            sm[SM_CPS + b * 36 + j4 + jj] = v;
        }
    }

    // ===== Phase C: caps_feat = relu([CP,1] @ Wm + bm), 32x128, K=33 =====
    __syncthreads();               // B readers done -> safe to overwrite W2S
#pragma unroll
    for (int p = 0; p < 5; ++p) {
        const int idx = t + p * 256;
        if (idx < 1056)
            *(float4*)&sm[SM_WM + idx * 4] = wmpf[p];
    }
    __syncthreads();
    // --- D2 prefetch setup: per-p source pointer/stride resolved ONCE (no
    // per-chunk div/mod/branches); chunk0 loads issue now, hide under C compute.
    const float* d2p[5]; int d2adv[5], d2dst[5]; float d2msk[5], d2pf[5];
#pragma unroll
    for (int p = 0; p < 5; ++p) {
        const int idx = t + p * 256;            // dest offset in [16][80] == idx
        const int kp = idx / 80, colp = idx - kp * 80;
        d2dst[p] = idx;
        const float* s; int st; float mk = 1.0f;
        if (colp < 6)       { s = &wccr[c * (DH * 6) + kp * 6 + colp];          st = 6;  }
        else if (colp == 6) { s = &wpc [c * DH + kp];                            st = 1;  }
        else if (colp < 43) { s = &wpv [c * (DH * NV) + kp * NV + (colp - 7)];   st = NV; }
        else if (colp < 79) { s = &wsv [c * (DH * NV) + kp * NV + (colp - 43)];  st = NV; }
        else                { s = &wccr[c * (DH * 6)]; st = 0; mk = 0.0f; }      // pad col 79
        d2pf[p]  = *s;
        d2p[p]   = s + st * 16;
        d2adv[p] = st * 16;
        d2msk[p] = mk;
    }
    float bpf = 0.0f;
    if (t < 80) {
        if (t < 6)       bpf = bccr[c * 6 + t];
        else if (t == 6) bpf = bpc[c];
        else if (t < 43) bpf = bpv[c * NV + (t - 7)];
        else if (t < 79) bpf = bsv[c * NV + (t - 43)];
    }
    {
        const int b  = t & 31;
        const int nb = (t >> 5) << 4;
        float acc[16] = {};
#pragma unroll
        for (int k4 = 0; k4 < 8; ++k4) {
            const float4 a4 = *(const float4*)&sm[SM_CPS + b * 36 + k4 * 4];
            const float aA[4] = { a4.x, a4.y, a4.z, a4.w };
#pragma unroll
            for (int kk = 0; kk < 4; ++kk) {
                const int k = k4 * 4 + kk;
#pragma unroll
                for (int jq = 0; jq < 4; ++jq) {
                    const float4 wv = *(const float4*)&sm[SM_WM + k * DH + nb + jq * 4];
                    acc[jq*4+0] += aA[kk] * wv.x; acc[jq*4+1] += aA[kk] * wv.y;
                    acc[jq*4+2] += aA[kk] * wv.z; acc[jq*4+3] += aA[kk] * wv.w;
                }
            }
        }
        // exist column (k=32) is constant 1.0 -> plain add of WM row 32
#pragma unroll
        for (int jq = 0; jq < 4; ++jq) {
            const float4 wv = *(const float4*)&sm[SM_WM + 32 * DH + nb + jq * 4];
            acc[jq*4+0] += wv.x; acc[jq*4+1] += wv.y; acc[jq*4+2] += wv.z; acc[jq*4+3] += wv.w;
        }
#pragma unroll
        for (int jq = 0; jq < 4; ++jq) {
            const float4 bmv = *(const float4*)&bm[c * DH + nb + jq * 4];
            sm[SM_FST + (nb + jq*4 + 0) * 36 + b] = fmaxf(acc[jq*4+0] + bmv.x, 0.0f);
            sm[SM_FST + (nb + jq*4 + 1) * 36 + b] = fmaxf(acc[jq*4+1] + bmv.y, 0.0f);
            sm[SM_FST + (nb + jq*4 + 2) * 36 + b] = fmaxf(acc[jq*4+2] + bmv.z, 0.0f);
            sm[SM_FST + (nb + jq*4 + 3) * 36 + b] = fmaxf(acc[jq*4+3] + bmv.w, 0.0f);
        }
    }

    // ===== Phase D2: heads [ccr|pres_caps|pres_vote|scale_vote], 32x80, K=128 =====
    {
        const int txx = t & 15;   // cols txx*5..+4
        const int tyy = t >> 4;   // rows tyy*2, tyy*2+1
        float acc[2][5] = {};
        for (int k0 = 0; k0 < DH; k0 += 16) {
            __syncthreads();      // first iter: WM readers (C) done before WH overwrite
#pragma unroll
            for (int p = 0; p < 5; ++p)
                sm[SM_WH + d2dst[p]] = d2msk[p] * d2pf[p];
            if (k0 == 0 && t < 80) sm[SM_HB + t] = bpf;
            __syncthreads();
            if (k0 + 16 < DH) {
#pragma unroll
                for (int p = 0; p < 5; ++p) {
                    d2pf[p] = *d2p[p];
                    d2p[p] += d2adv[p];
                }
            }
#pragma unroll
            for (int kk = 0; kk < 16; ++kk) {
                const float2 av = *(const float2*)&sm[SM_FST + (k0 + kk) * 36 + tyy * 2];
#pragma unroll
                for (int j = 0; j < 5; ++j) {
                    const float w = sm[SM_WH + kk * 80 + txx * 5 + j];
                    acc[0][j] += av.x * w;
                    acc[1][j] += av.y * w;
                }
            }
        }
#pragma unroll
        for (int i = 0; i < 2; ++i)
#pragma unroll
            for (int j = 0; j < 5; ++j)
                sm[SM_HD + (tyy * 2 + i) * 81 + txx * 5 + j] = acc[i][j];
    }

    // --- D4 prefetch chunk 0: issued here so it hides under D2b/D2c epilogues.
    const float* d4p[7]; int d4dst[7]; unsigned d4v = 0; float2 d4pf[7];
    {
        const float* wdyb = &wdy[c * (DH * 216)];
#pragma unroll
        for (int p = 0; p < 7; ++p) {
            const int e2  = (t + p * 256) * 2;
            const int row = e2 / 224, col = e2 - row * 224;
            d4dst[p] = row * 224 + col;
            d4pf[p]  = make_float2(0.0f, 0.0f);
            d4p[p]   = wdyb;
            if (col < 216) {
                d4v |= 1u << p;
                d4p[p]  = wdyb + row * 216 + col;
                d4pf[p] = *(const float2*)d4p[p];
                d4p[p] += 16 * 216;
            }
        }
    }
    __syncthreads();

    // D2b: ccr matrices + pres_caps sigmoid
    if (t < 32) {
        const int b = t;
        const float plc = sm[SM_HD + b * 81 + 6] + sm[SM_HB + 6];
        out[OFF3 + (rb + b) * NC + c] = plc;
        sm[SM_PSIG + b] = sigm(plc);
        float pp[6], m[6];
#pragma unroll
        for (int i = 0; i < 6; ++i) pp[i] = sm[SM_HD + b * 81 + i] + sm[SM_HB + i];
        geo(pp, m);
#pragma unroll
        for (int i = 0; i < 6; ++i) sm[SM_M + b * 6 + i] = m[i];
    }
    __syncthreads();

    // D2c: pres_vote / scale_vote epilogues
#pragma unroll
    for (int p = 0; p < 10; ++p) {
        const int item = t + p * 256;
        const int b = item / 80, col = item % 80;
        if (col >= 7 && col < 79) {
            const float v = sm[SM_HD + b * 81 + col] + sm[SM_HB + col];
            const int base = ((rb + b) * NC + c) * NV;
            if (col < 43) {
                const int o = col - 7;
                out[OFF4 + base + o] = v;
                out[OFF2 + base + o] = sm[SM_PSIG + b] * sigm(v);
            } else {
                const int o = col - 43;
                float sp = v + 0.5f;
                sp = (sp > 15.0f) ? sp : log1pf(__expf(sp));
                out[OFF1 + base + o] = sp + 0.01f;
            }
        }
    }

    // ===== Phase D4: cpr_dynamic = F @ Wdyn, 32x216(pad 224), K=128 =====
    float l2loc = 0.0f;
    {
        const int g   = t & 63;    // col group: cols 4g..4g+3 (g>=54 = padding)
        const int ty4 = t >> 6;    // rows ty4*8..+7 (wave-uniform -> broadcast reads)
        float acc[8][4] = {};
        for (int k0 = 0; k0 < DH; k0 += 16) {
            __syncthreads();       // first iter: HD readers (D2c) done before WD overwrite
#pragma unroll
            for (int p = 0; p < 7; ++p)
                *(float2*)&sm[SM_WD + d4dst[p]] = d4pf[p];
            __syncthreads();
            if (k0 + 16 < DH) {
#pragma unroll
                for (int p = 0; p < 7; ++p) {
                    if ((d4v >> p) & 1) {
                        d4pf[p] = *(const float2*)d4p[p];
                        d4p[p] += 16 * 216;
                    }
                }
            }
#pragma unroll
            for (int kk = 0; kk < 16; ++kk) {
                const float4 a0 = *(const float4*)&sm[SM_FST + (k0 + kk) * 36 + ty4 * 8];
                const float4 a1 = *(const float4*)&sm[SM_FST + (k0 + kk) * 36 + ty4 * 8 + 4];
                const float4 w  = *(const float4*)&sm[SM_WD + kk * 224 + g * 4];
                acc[0][0] += a0.x * w.x; acc[0][1] += a0.x * w.y; acc[0][2] += a0.x * w.z; acc[0][3] += a0.x * w.w;
                acc[1][0] += a0.y * w.x; acc[1][1] += a0.y * w.y; acc[1][2] += a0.y * w.z; acc[1][3] += a0.y * w.w;
                acc[2][0] += a0.z * w.x; acc[2][1] += a0.z * w.y; acc[2][2] += a0.z * w.z; acc[2][3] += a0.z * w.w;
                acc[3][0] += a0.w * w.x; acc[3][1] += a0.w * w.y; acc[3][2] += a0.w * w.z; acc[3][3] += a0.w * w.w;
                acc[4][0] += a1.x * w.x; acc[4][1] += a1.x * w.y; acc[4][2] += a1.x * w.z; acc[4][3] += a1.x * w.w;
                acc[5][0] += a1.y * w.x; acc[5][1] += a1.y * w.y; acc[5][2] += a1.y * w.z; acc[5][3] += a1.y * w.w;
                acc[6][0] += a1.z * w.x; acc[6][1] += a1.z * w.y; acc[6][2] += a1.z * w.z; acc[6][3] += a1.z * w.w;
                acc[7][0] += a1.w * w.x; acc[7][1] += a1.w * w.y; acc[7][2] += a1.w * w.z; acc[7][3] += a1.w * w.w;
            }
        }
        // two halves of 108 cols: write DYN, then epilogue
        for (int half = 0; half < 2; ++half) {
            __syncthreads();   // prior WD/DYN readers done
            if (g < 54 && (g >= 27) == (half == 1)) {
#pragma unroll
                for (int i = 0; i < 8; ++i)
#pragma unroll
                    for (int j = 0; j < 4; ++j)
                        sm[SM_DYN + (ty4 * 8 + i) * 109 + (g * 4 + j - half * 108)] = acc[i][j];
            }
            __syncthreads();
#pragma unroll
            for (int p = 0; p < 3; ++p) {
                const int item = t + p * 256;
                if (item < 576) {
                    const int b = item / 18, vh = item % 18;
                    const int v = half * 18 + vh;
                    float dyn[6], pose[6], mB[6];
                    float ss = 0.0f;
#pragma unroll
                    for (int j = 0; j < 6; ++j) {
                        dyn[j] = sm[SM_DYN + b * 109 + vh * 6 + j];
                        ss += dyn[j] * dyn[j];
                        pose[j] = dyn[j] + cst[c * (NV * 6) + v * 6 + j];
                    }
                    l2loc += ss;
                    geo(pose, mB);
                    const float A0 = sm[SM_M + b * 6 + 0], A1 = sm[SM_M + b * 6 + 1];
                    const float A2 = sm[SM_M + b * 6 + 2], A3 = sm[SM_M + b * 6 + 3];
                    const float A4 = sm[SM_M + b * 6 + 4], A5 = sm[SM_M + b * 6 + 5];
                    const int ob = (((rb + b) * NC + c) * NV + v) * 9;
                    out[OFF0 + ob + 0] = A0 * mB[0] + A1 * mB[3];
                    out[OFF0 + ob + 1] = A0 * mB[1] + A1 * mB[4];
                    out[OFF0 + ob + 2] = A0 * mB[2] + A1 * mB[5] + A2;
                    out[OFF0 + ob + 3] = A3 * mB[0] + A4 * mB[3];
                    out[OFF0 + ob + 4] = A3 * mB[1] + A4 * mB[4];
                    out[OFF0 + ob + 5] = A3 * mB[2] + A4 * mB[5] + A5;
                    out[OFF0 + ob + 6] = 0.0f;
                    out[OFF0 + ob + 7] = 0.0f;
                    out[OFF0 + ob + 8] = 1.0f;
                }
            }
        }
    }

    // L2 scalar: wave reduce, one atomic per wave; /B/2 = /2048
    l2loc += __shfl_down(l2loc, 32, 64);
    l2loc += __shfl_down(l2loc, 16, 64);
    l2loc += __shfl_down(l2loc, 8, 64);
    l2loc += __shfl_down(l2loc, 4, 64);
    l2loc += __shfl_down(l2loc, 2, 64);
    l2loc += __shfl_down(l2loc, 1, 64);
    if ((t & 63) == 0) atomicAdd(&out[OFF5], l2loc * (1.0f / 2048.0f));
}

extern "C" void kernel_launch(void* const* d_in, const int* in_sizes, int n_in,
                              void* d_out, int out_size, void* d_ws, size_t ws_size,
                              hipStream_t stream)
{
    const float* feat = (const float*)d_in[0];
    const float* w1   = (const float*)d_in[1];
    const float* b1   = (const float*)d_in[2];
    const float* w2   = (const float*)d_in[3];
    const float* b2   = (const float*)d_in[4];
    const float* wm   = (const float*)d_in[5];
    const float* bm   = (const float*)d_in[6];
    const float* wdy  = (const float*)d_in[7];
    const float* wccr = (const float*)d_in[8];
    const float* bccr = (const float*)d_in[9];
    const float* wpc  = (const float*)d_in[10];
    const float* bpc  = (const float*)d_in[11];
    const float* wpv  = (const float*)d_in[12];
    const float* bpv  = (const float*)d_in[13];
    const float* wsv  = (const float*)d_in[14];
    const float* bsv  = (const float*)d_in[15];
    const float* cst  = (const float*)d_in[16];
    float* out = (float*)d_out;

    zero_l2_kernel<<<1, 1, 0, stream>>>(out);
    caps_fused_kernel<<<2048, 256, 0, stream>>>(feat, w1, b1, w2, b2, wm, bm, wdy,
                                                wccr, bccr, wpc, bpc, wpv, bpv,
                                                wsv, bsv, cst, out);
}